// Round 5
// baseline (216.639 us; speedup 1.0000x reference)
//
#include <hip/hip_runtime.h>
#include <hip/hip_bf16.h>

#define TT 200
#define BB 64
#define TB (TT*BB)          // 12800 rows
#define NL2E (-1.44269504088896f)

#define C4(v,kk) (((const float*)&(v))[kk])

__device__ __forceinline__ float sigm_fast(float x) {
    return __builtin_amdgcn_rcpf(1.0f + __builtin_amdgcn_exp2f(NL2E * x));
}
__device__ __forceinline__ float leaky(float x) {
    return x >= 0.0f ? x : 0.3f * x;
}

// ---- K1: x1e = exp2(NL2E*(inp@w1+b1));  qbuf = inp@w2 (raw x2);  y3 = inp@w3 ----
__global__ __launch_bounds__(256) void gemm3_kernel(
    const float* __restrict__ inputs,
    const float* __restrict__ w1k, const float* __restrict__ w1b,
    const float* __restrict__ w2k, const float* __restrict__ w3k,
    float* __restrict__ x1e, float* __restrict__ qbuf, float* __restrict__ y3)
{
    __shared__ __align__(16) float w1s[4096], w2s[4096], w3s[4096], b1s[64];
    __shared__ float4 rows4[4][4][16];    // [wave][row][k4] -- wave-private
    int t = threadIdx.x;
    for (int i = t; i < 4096; i += 256) { w1s[i] = w1k[i]; w2s[i] = w2k[i]; w3s[i] = w3k[i]; }
    if (t < 64) b1s[t] = w1b[t];
    __syncthreads();
    int wv = t >> 6, lane = t & 63;
    int rr = lane >> 4, k4s = lane & 15;
    for (int r0 = blockIdx.x * 16; r0 < TB; r0 += gridDim.x * 16) {
        int rb = r0 + wv * 4;
        rows4[wv][rr][k4s] = *(const float4*)&inputs[(rb + rr) * 64 + k4s * 4];
        float a1_0 = b1s[lane], a1_1 = b1s[lane], a1_2 = b1s[lane], a1_3 = b1s[lane];
        float a2_0 = 0.f, a2_1 = 0.f, a2_2 = 0.f, a2_3 = 0.f;
        float a3_0 = 0.f, a3_1 = 0.f, a3_2 = 0.f, a3_3 = 0.f;
        #pragma unroll 4
        for (int k4 = 0; k4 < 16; k4++) {
            float4 x0 = rows4[wv][0][k4];
            float4 x1 = rows4[wv][1][k4];
            float4 x2 = rows4[wv][2][k4];
            float4 x3 = rows4[wv][3][k4];
            #pragma unroll
            for (int kk = 0; kk < 4; kk++) {
                int k = k4 * 4 + kk;
                float W1 = w1s[k * 64 + lane];
                float W2 = w2s[k * 64 + lane];
                float W3 = w3s[k * 64 + lane];
                float v0 = C4(x0, kk), v1 = C4(x1, kk), v2 = C4(x2, kk), v3 = C4(x3, kk);
                a1_0 += v0 * W1; a1_1 += v1 * W1; a1_2 += v2 * W1; a1_3 += v3 * W1;
                a2_0 += v0 * W2; a2_1 += v1 * W2; a2_2 += v2 * W2; a2_3 += v3 * W2;
                a3_0 += v0 * W3; a3_1 += v1 * W3; a3_2 += v2 * W3; a3_3 += v3 * W3;
            }
        }
        x1e[(rb    ) * 64 + lane] = __builtin_amdgcn_exp2f(NL2E * a1_0);
        x1e[(rb + 1) * 64 + lane] = __builtin_amdgcn_exp2f(NL2E * a1_1);
        x1e[(rb + 2) * 64 + lane] = __builtin_amdgcn_exp2f(NL2E * a1_2);
        x1e[(rb + 3) * 64 + lane] = __builtin_amdgcn_exp2f(NL2E * a1_3);
        qbuf[(rb    ) * 64 + lane] = a2_0;
        qbuf[(rb + 1) * 64 + lane] = a2_1;
        qbuf[(rb + 2) * 64 + lane] = a2_2;
        qbuf[(rb + 3) * 64 + lane] = a2_3;
        y3[(rb    ) * 64 + lane] = a3_0;
        y3[(rb + 1) * 64 + lane] = a3_1;
        y3[(rb + 2) * 64 + lane] = a3_2;
        y3[(rb + 3) * 64 + lane] = a3_3;
    }
}

// ---- K2: qe = exp2(NL2E*(x2 + cumsum_t(y3)/(t+1)))  (in-place on qbuf) ----
// 64 blocks (one per b) x 256 threads (4 chunks x 64 h). Scan values register-stashed.
__global__ __launch_bounds__(256) void cumsum_kernel(
    const float* __restrict__ y3, float* __restrict__ qe)
{
    __shared__ float part[4][64];
    int b = blockIdx.x, t = threadIdx.x;
    int c = t >> 6, h = t & 63;
    int base = b * 64 + h;
    const int L = 50;                      // 200 / 4 chunks
    int t0 = c * L;
    float vals[L];
    float s = 0.f;
    #pragma unroll
    for (int i = 0; i < L; i++) {
        vals[i] = y3[(t0 + i) * 4096 + base];
        s += vals[i];
    }
    part[c][h] = s;
    __syncthreads();
    float acc = 0.f;
    #pragma unroll
    for (int cc = 0; cc < 3; cc++) acc += (cc < c) ? part[cc][h] : 0.f;
    #pragma unroll
    for (int i = 0; i < L; i++) {
        int tt = t0 + i;
        int idx = tt * 4096 + base;
        acc += vals[i];
        float q = qe[idx] + acc / (float)(tt + 1);
        qe[idx] = __builtin_amdgcn_exp2f(NL2E * q);
    }
}

// ---- K3: s[i,j] = sum_h w0[h] / (1 + Eq[i,h]*E1[j,h])  (j<=i);  m_a = S @ inputs ----
// q-row held in registers (loaded once, clamped); LDS = xt+pt+St2 ~ 22 KB.
__global__ __launch_bounds__(256) void scores_kernel(
    const float* __restrict__ x1e, const float* __restrict__ qe,
    const float* __restrict__ inputs, const float* __restrict__ w0k,
    float* __restrict__ m_a)
{
    __shared__ __align__(16) float xt[32 * 68];
    __shared__ __align__(16) float pt[32 * 68];
    __shared__ __align__(16) float St2[32 * 36];   // [j][i] transposed
    __shared__ __align__(16) float w0s[64];
    int t = threadIdx.x;
    int b = blockIdx.x, it = 6 - blockIdx.y;       // LPT: heavy tiles dispatched first
    int i0 = it * 32;
    int ilA = t & 31, jg = t >> 5;                 // jg in 0..7

    // q row of this thread, in registers (loop-invariant across jt)
    float4 qreg[16];
    {
        int gq = i0 + ilA; if (gq > TT - 1) gq = TT - 1;   // clamp: masked later
        const float* qrow = qe + gq * 4096 + b * 64;
        #pragma unroll
        for (int h4 = 0; h4 < 16; h4++) qreg[h4] = *(const float4*)&qrow[h4 * 4];
    }
    if (t < 64) w0s[t] = w0k[t];

    int wv = t >> 6, e = t & 63;
    int il0 = wv * 8;
    float acc[8] = {0.f,0.f,0.f,0.f,0.f,0.f,0.f,0.f};

    for (int jt = 0; jt <= it; jt++) {
        int j0 = jt * 32;
        __syncthreads();   // previous stage2 done before overwriting xt/pt
        for (int i = t; i < 2048; i += 256) {
            int r = i >> 6, h = i & 63;
            int gj = j0 + r;
            bool v = (gj < TT);
            xt[r * 68 + h] = v ? x1e[gj * 4096 + b * 64 + h] : 0.f;
            pt[r * 68 + h] = v ? inputs[gj * 4096 + b * 64 + h] : 0.f;
        }
        __syncthreads();   // also covers w0s (first iteration)
        // stage 1: 4 score entries per thread: (ilA, jg + {0,8,16,24})
        float s0 = 0.f, s1 = 0.f, s2 = 0.f, s3 = 0.f;
        #pragma unroll 4
        for (int h4 = 0; h4 < 16; h4++) {
            float4 q4 = qreg[h4];
            float4 w4 = *(const float4*)&w0s[h4 * 4];
            float4 xA = *(const float4*)&xt[(jg     ) * 68 + h4 * 4];
            float4 xB = *(const float4*)&xt[(jg +  8) * 68 + h4 * 4];
            float4 xC = *(const float4*)&xt[(jg + 16) * 68 + h4 * 4];
            float4 xD = *(const float4*)&xt[(jg + 24) * 68 + h4 * 4];
            #pragma unroll
            for (int kk = 0; kk < 4; kk++) {
                float qv = C4(q4, kk), w = C4(w4, kk);
                s0 += w * __builtin_amdgcn_rcpf(1.f + qv * C4(xA, kk));
                s1 += w * __builtin_amdgcn_rcpf(1.f + qv * C4(xB, kk));
                s2 += w * __builtin_amdgcn_rcpf(1.f + qv * C4(xC, kk));
                s3 += w * __builtin_amdgcn_rcpf(1.f + qv * C4(xD, kk));
            }
        }
        {
            int gi = i0 + ilA, gj = j0 + jg;
            St2[(jg     ) * 36 + ilA] = (gj      <= gi && gi < TT) ? s0 : 0.f;
            St2[(jg +  8) * 36 + ilA] = (gj +  8 <= gi && gi < TT) ? s1 : 0.f;
            St2[(jg + 16) * 36 + ilA] = (gj + 16 <= gi && gi < TT) ? s2 : 0.f;
            St2[(jg + 24) * 36 + ilA] = (gj + 24 <= gi && gi < TT) ? s3 : 0.f;
        }
        __syncthreads();
        // stage 2: wave wv owns i-rows il0..il0+7, lane owns e
        #pragma unroll 4
        for (int jl = 0; jl < 32; jl++) {
            float v = pt[jl * 68 + e];
            float4 sA = *(const float4*)&St2[jl * 36 + il0];
            float4 sB = *(const float4*)&St2[jl * 36 + il0 + 4];
            acc[0] += C4(sA,0) * v; acc[1] += C4(sA,1) * v;
            acc[2] += C4(sA,2) * v; acc[3] += C4(sA,3) * v;
            acc[4] += C4(sB,0) * v; acc[5] += C4(sB,1) * v;
            acc[6] += C4(sB,2) * v; acc[7] += C4(sB,3) * v;
        }
    }
    #pragma unroll
    for (int k2 = 0; k2 < 8; k2++) {
        int gi = i0 + il0 + k2;
        if (gi < TT) m_a[gi * 4096 + b * 64 + e] = acc[k2];
    }
}

// ---- K4: fused pc+pv heads. 400 blocks x 32 rows, 8 rows/wave, two weight phases ----
// LDS = 32 KB weights + 16 KB acts = 48 KB (3 blocks/CU). Layer-0 output overwrites
// acts in place (same-wave, in-order LDS); pv phase re-stages raw acts from global.
__global__ __launch_bounds__(256) void mlp2_kernel(
    const float* __restrict__ ma, const float* __restrict__ inputs,
    const float* __restrict__ pc_a0k, const float* __restrict__ pc_a0b,
    const float* __restrict__ pc_b0k, const float* __restrict__ pc_b0b,
    const float* __restrict__ pc_a1k, const float* __restrict__ pc_a1b,
    const float* __restrict__ pc_b1k, const float* __restrict__ pc_b1b,
    const float* __restrict__ pv_a0k, const float* __restrict__ pv_a0b,
    const float* __restrict__ pv_b0k, const float* __restrict__ pv_b0b,
    const float* __restrict__ pv_a1k, const float* __restrict__ pv_a1b,
    const float* __restrict__ pv_b1k, const float* __restrict__ pv_b1b,
    float* __restrict__ outp)
{
    __shared__ __align__(16) float wA0[4096], wB0[4096];   // 32 KB
    __shared__ __align__(16) float acts[4][8][2][64];      // 16 KB: raw, then l0 in place
    int t = threadIdx.x, wv = t >> 6, lane = t & 63;
    int tw = lane >> 5, h2 = lane & 31;

    // stage raw activations (wave-private: acts[wv] only touched by wave wv)
    auto stage_acts = [&]() {
        float4* a4 = (float4*)&acts[wv][0][0][0];
        #pragma unroll
        for (int p = 0; p < 4; p++) {
            int fw = p * 64 + lane;            // 0..255 across the wave
            int r = fw >> 5, src = (fw >> 4) & 1, k4 = fw & 15;
            int row = blockIdx.x * 32 + wv * 8 + r;
            const float* sp = src ? inputs : ma;
            a4[fw] = *(const float4*)&sp[row * 64 + k4 * 4];
        }
    };

    stage_acts();
    for (int i = t; i < 4096; i += 256) { wA0[i] = pc_a0k[i]; wB0[i] = pc_b0k[i]; }
    __syncthreads();

    float pcr[8];
    // ---------- phase pc ----------
    {
        float bA = pc_a0b[lane], bB = pc_b0b[lane];
        float accA[8], accB[8];
        #pragma unroll
        for (int r = 0; r < 8; r++) { accA[r] = bA; accB[r] = bB; }
        #pragma unroll 4
        for (int k4 = 0; k4 < 16; k4++) {
            float4 aA[8], aB[8];
            #pragma unroll
            for (int r = 0; r < 8; r++) {
                aA[r] = *(const float4*)&acts[wv][r][0][k4 * 4];
                aB[r] = *(const float4*)&acts[wv][r][1][k4 * 4];
            }
            #pragma unroll
            for (int kk = 0; kk < 4; kk++) {
                float wAv = wA0[(k4 * 4 + kk) * 64 + lane];
                float wBv = wB0[(k4 * 4 + kk) * 64 + lane];
                #pragma unroll
                for (int r = 0; r < 8; r++) {
                    accA[r] += C4(aA[r], kk) * wAv;
                    accB[r] += C4(aB[r], kk) * wBv;
                }
            }
        }
        // layer-0 out overwrites acts (same wave, in-order LDS)
        #pragma unroll
        for (int r = 0; r < 8; r++) {
            acts[wv][r][0][lane] = leaky(accA[r]);
            acts[wv][r][1][lane] = leaky(accB[r]);
        }
        const float* w1p = tw ? pc_b1k : pc_a1k;
        float b1 = (tw ? pc_b1b : pc_a1b)[h2];
        float o[8];
        #pragma unroll
        for (int r = 0; r < 8; r++) o[r] = b1;
        for (int k = 0; k < 64; k++) {
            float w1 = w1p[k * 32 + h2];
            #pragma unroll
            for (int r = 0; r < 8; r++) o[r] += acts[wv][r][tw][k] * w1;
        }
        #pragma unroll
        for (int r = 0; r < 8; r++) {
            float po = leaky(o[r]);
            float pr = po * __shfl_xor(po, 32);
            #pragma unroll
            for (int m = 1; m <= 16; m <<= 1) pr += __shfl_xor(pr, m);
            pcr[r] = pr;    // valid at lane 0
        }
    }
    __syncthreads();   // all waves done with pc weights
    for (int i = t; i < 4096; i += 256) { wA0[i] = pv_a0k[i]; wB0[i] = pv_b0k[i]; }
    stage_acts();      // restore raw acts over l0 (wave-private, no barrier needed)
    __syncthreads();
    // ---------- phase pv ----------
    {
        float bA = pv_a0b[lane], bB = pv_b0b[lane];
        float accA[8], accB[8];
        #pragma unroll
        for (int r = 0; r < 8; r++) { accA[r] = bA; accB[r] = bB; }
        #pragma unroll 4
        for (int k4 = 0; k4 < 16; k4++) {
            float4 aA[8], aB[8];
            #pragma unroll
            for (int r = 0; r < 8; r++) {
                aA[r] = *(const float4*)&acts[wv][r][0][k4 * 4];
                aB[r] = *(const float4*)&acts[wv][r][1][k4 * 4];
            }
            #pragma unroll
            for (int kk = 0; kk < 4; kk++) {
                float wAv = wA0[(k4 * 4 + kk) * 64 + lane];
                float wBv = wB0[(k4 * 4 + kk) * 64 + lane];
                #pragma unroll
                for (int r = 0; r < 8; r++) {
                    accA[r] += C4(aA[r], kk) * wAv;
                    accB[r] += C4(aB[r], kk) * wBv;
                }
            }
        }
        #pragma unroll
        for (int r = 0; r < 8; r++) {
            acts[wv][r][0][lane] = leaky(accA[r]);
            acts[wv][r][1][lane] = leaky(accB[r]);
        }
        const float* w1p = tw ? pv_b1k : pv_a1k;
        float b1 = (tw ? pv_b1b : pv_a1b)[h2];
        float o[8];
        #pragma unroll
        for (int r = 0; r < 8; r++) o[r] = b1;
        for (int k = 0; k < 64; k++) {
            float w1 = w1p[k * 32 + h2];
            #pragma unroll
            for (int r = 0; r < 8; r++) o[r] += acts[wv][r][tw][k] * w1;
        }
        #pragma unroll
        for (int r = 0; r < 8; r++) {
            float po = leaky(o[r]);
            float pr = po * __shfl_xor(po, 32);
            #pragma unroll
            for (int m = 1; m <= 16; m <<= 1) pr += __shfl_xor(pr, m);
            if (lane == 0) {
                int row = blockIdx.x * 32 + wv * 8 + r;
                float spc = sigm_fast(pcr[r]);
                outp[row] = spc;
                outp[TB + row] = sigm_fast(pr) * spc;
            }
        }
    }
}

extern "C" void kernel_launch(void* const* d_in, const int* in_sizes, int n_in,
                              void* d_out, int out_size, void* d_ws, size_t ws_size,
                              hipStream_t stream) {
    const float* inputs = (const float*)d_in[0];
    const float* w1k = (const float*)d_in[1];
    const float* w1b = (const float*)d_in[2];
    const float* w2k = (const float*)d_in[3];
    const float* w3k = (const float*)d_in[4];
    const float* w0k = (const float*)d_in[5];
    float* out = (float*)d_out;
    float* ws  = (float*)d_ws;
    float* x1e  = ws;                  // exp2(-log2e * x1)
    float* qbuf = ws + 819200;         // x2, then exp2(-log2e * q) in place
    float* y3   = ws + 2 * 819200;     // y3 until K2; reused as ma by K3/K4
    float* ma   = y3;                  // alias: y3 dead after cumsum_kernel

    gemm3_kernel<<<dim3(400), 256, 0, stream>>>(inputs, w1k, w1b, w2k, w3k, x1e, qbuf, y3);
    cumsum_kernel<<<dim3(64), 256, 0, stream>>>(y3, qbuf);
    scores_kernel<<<dim3(64, 7), 256, 0, stream>>>(x1e, qbuf, inputs, w0k, ma);
    mlp2_kernel<<<dim3(400), 256, 0, stream>>>(ma, inputs,
        (const float*)d_in[6],  (const float*)d_in[7],  (const float*)d_in[8],  (const float*)d_in[9],
        (const float*)d_in[10], (const float*)d_in[11], (const float*)d_in[12], (const float*)d_in[13],
        (const float*)d_in[14], (const float*)d_in[15], (const float*)d_in[16], (const float*)d_in[17],
        (const float*)d_in[18], (const float*)d_in[19], (const float*)d_in[20], (const float*)d_in[21],
        out);
}

// Round 6
// 176.755 us; speedup vs baseline: 1.2256x; 1.2256x over previous
//
#include <hip/hip_runtime.h>
#include <hip/hip_bf16.h>

#define TT 200
#define BB 64
#define TB (TT*BB)          // 12800 rows
#define SLICE 819200        // floats per [T,B,H] buffer
#define NL2E (-1.44269504088896f)

#define C4(v,kk) (((const float*)&(v))[kk])

__device__ __forceinline__ float sigm_fast(float x) {
    return __builtin_amdgcn_rcpf(1.0f + __builtin_amdgcn_exp2f(NL2E * x));
}
__device__ __forceinline__ float leaky(float x) {
    return x >= 0.0f ? x : 0.3f * x;
}

// ---- K1: x1e = exp2(NL2E*(inp@w1+b1));  qbuf = inp@w2 (raw x2);  y3 = inp@w3 ----
// 800 blocks x 16 rows, single pass.
__global__ __launch_bounds__(256) void gemm3_kernel(
    const float* __restrict__ inputs,
    const float* __restrict__ w1k, const float* __restrict__ w1b,
    const float* __restrict__ w2k, const float* __restrict__ w3k,
    float* __restrict__ x1e, float* __restrict__ qbuf, float* __restrict__ y3)
{
    __shared__ __align__(16) float w1s[4096], w2s[4096], w3s[4096], b1s[64];
    __shared__ float4 rows4[4][4][16];    // [wave][row][k4] -- wave-private
    int t = threadIdx.x;
    for (int i = t; i < 4096; i += 256) { w1s[i] = w1k[i]; w2s[i] = w2k[i]; w3s[i] = w3k[i]; }
    if (t < 64) b1s[t] = w1b[t];
    int wv = t >> 6, lane = t & 63;
    int rr = lane >> 4, k4s = lane & 15;
    int rb = blockIdx.x * 16 + wv * 4;
    rows4[wv][rr][k4s] = *(const float4*)&inputs[(rb + rr) * 64 + k4s * 4];
    __syncthreads();
    float a1_0 = b1s[lane], a1_1 = b1s[lane], a1_2 = b1s[lane], a1_3 = b1s[lane];
    float a2_0 = 0.f, a2_1 = 0.f, a2_2 = 0.f, a2_3 = 0.f;
    float a3_0 = 0.f, a3_1 = 0.f, a3_2 = 0.f, a3_3 = 0.f;
    #pragma unroll 4
    for (int k4 = 0; k4 < 16; k4++) {
        float4 x0 = rows4[wv][0][k4];
        float4 x1 = rows4[wv][1][k4];
        float4 x2 = rows4[wv][2][k4];
        float4 x3 = rows4[wv][3][k4];
        #pragma unroll
        for (int kk = 0; kk < 4; kk++) {
            int k = k4 * 4 + kk;
            float W1 = w1s[k * 64 + lane];
            float W2 = w2s[k * 64 + lane];
            float W3 = w3s[k * 64 + lane];
            float v0 = C4(x0, kk), v1 = C4(x1, kk), v2 = C4(x2, kk), v3 = C4(x3, kk);
            a1_0 += v0 * W1; a1_1 += v1 * W1; a1_2 += v2 * W1; a1_3 += v3 * W1;
            a2_0 += v0 * W2; a2_1 += v1 * W2; a2_2 += v2 * W2; a2_3 += v3 * W2;
            a3_0 += v0 * W3; a3_1 += v1 * W3; a3_2 += v2 * W3; a3_3 += v3 * W3;
        }
    }
    x1e[(rb    ) * 64 + lane] = __builtin_amdgcn_exp2f(NL2E * a1_0);
    x1e[(rb + 1) * 64 + lane] = __builtin_amdgcn_exp2f(NL2E * a1_1);
    x1e[(rb + 2) * 64 + lane] = __builtin_amdgcn_exp2f(NL2E * a1_2);
    x1e[(rb + 3) * 64 + lane] = __builtin_amdgcn_exp2f(NL2E * a1_3);
    qbuf[(rb    ) * 64 + lane] = a2_0;
    qbuf[(rb + 1) * 64 + lane] = a2_1;
    qbuf[(rb + 2) * 64 + lane] = a2_2;
    qbuf[(rb + 3) * 64 + lane] = a2_3;
    y3[(rb    ) * 64 + lane] = a3_0;
    y3[(rb + 1) * 64 + lane] = a3_1;
    y3[(rb + 2) * 64 + lane] = a3_2;
    y3[(rb + 3) * 64 + lane] = a3_3;
}

// ---- K2: qe = exp2(NL2E*(x2 + cumsum_t(y3)/(t+1)))  (in-place on qbuf) ----
// 128 blocks x 256 threads: (b, h-half); 8 chunks x 32 h, L=25. Low reg pressure.
__global__ __launch_bounds__(256) void cumsum_kernel(
    const float* __restrict__ y3, float* __restrict__ qe)
{
    __shared__ float part[8][32];
    int t = threadIdx.x;
    int c = t >> 5, hh = t & 31;
    int b = blockIdx.x >> 1;
    int h = ((blockIdx.x & 1) << 5) + hh;
    int base = b * 64 + h;
    const int L = 25;
    int t0 = c * L;
    float s = 0.f;
    for (int i = 0; i < L; i++) s += y3[(t0 + i) * 4096 + base];
    part[c][hh] = s;
    __syncthreads();
    float acc = 0.f;
    for (int cc = 0; cc < c; cc++) acc += part[cc][hh];
    for (int i = 0; i < L; i++) {
        int tt = t0 + i;
        int idx = tt * 4096 + base;
        acc += y3[idx];
        float q = qe[idx] + acc / (float)(tt + 1);
        qe[idx] = __builtin_amdgcn_exp2f(NL2E * q);
    }
}

// ---- K3: s[i,j] = sum_h w0[h] / (1 + Eq[i,h]*E1[j,h])  (j<=i);  ma_p = S_p @ inputs ----
// grid dim3(64, 7*S): b = blockIdx.x; it = 6 - yy/S (LPT), p = yy%S; jt = p, p+S, ... <= it
// q-tile in LDS (stride 66: 2-way aliasing = free). Partial m_a written per parity slice.
__global__ __launch_bounds__(256) void scores_kernel(
    const float* __restrict__ x1e, const float* __restrict__ qe,
    const float* __restrict__ inputs, const float* __restrict__ w0k,
    float* __restrict__ ma, int S)
{
    __shared__ __align__(16) float qt[32 * 66];
    __shared__ __align__(16) float xt[32 * 68];
    __shared__ __align__(16) float pt[32 * 68];
    __shared__ __align__(16) float St2[32 * 36];   // [j][i] transposed
    __shared__ __align__(16) float w0s[64];
    int t = threadIdx.x;
    int b = blockIdx.x;
    int yy = blockIdx.y;
    int it = 6 - yy / S;
    int p  = yy % S;
    int i0 = it * 32;
    int ilA = t & 31, jg = t >> 5;                 // jg in 0..7
    int wv = t >> 6, e = t & 63;
    int il0 = wv * 8;
    float acc[8] = {0.f,0.f,0.f,0.f,0.f,0.f,0.f,0.f};
    float* maP = ma + (size_t)p * SLICE;

    if (p <= it) {          // uniform branch: whole block has work
        // stage q tile (float2, stride 66)
        for (int i2 = t; i2 < 1024; i2 += 256) {
            int r = i2 >> 5, c2 = i2 & 31;
            int gq = i0 + r; if (gq > TT - 1) gq = TT - 1;
            *(float2*)&qt[r * 66 + c2 * 2] = *(const float2*)&qe[gq * 4096 + b * 64 + c2 * 2];
        }
        if (t < 64) w0s[t] = w0k[t];

        for (int jt = p; jt <= it; jt += S) {
            int j0 = jt * 32;
            __syncthreads();   // prev stage2 done (and first-iter qt/w0s visible)
            for (int i4 = t; i4 < 512; i4 += 256) {
                int r = i4 >> 4, c4 = i4 & 15;
                int gj = j0 + r;
                if (gj < TT) {
                    *(float4*)&xt[r * 68 + c4 * 4] = *(const float4*)&x1e[gj * 4096 + b * 64 + c4 * 4];
                    *(float4*)&pt[r * 68 + c4 * 4] = *(const float4*)&inputs[gj * 4096 + b * 64 + c4 * 4];
                } else {
                    *(float4*)&xt[r * 68 + c4 * 4] = make_float4(0.f, 0.f, 0.f, 0.f);
                    *(float4*)&pt[r * 68 + c4 * 4] = make_float4(0.f, 0.f, 0.f, 0.f);
                }
            }
            __syncthreads();
            // stage 1: 4 score entries per thread: (ilA, jg + {0,8,16,24})
            float s0 = 0.f, s1 = 0.f, s2 = 0.f, s3 = 0.f;
            #pragma unroll 4
            for (int h4 = 0; h4 < 16; h4++) {
                float4 w4 = *(const float4*)&w0s[h4 * 4];
                float4 xA = *(const float4*)&xt[(jg     ) * 68 + h4 * 4];
                float4 xB = *(const float4*)&xt[(jg +  8) * 68 + h4 * 4];
                float4 xC = *(const float4*)&xt[(jg + 16) * 68 + h4 * 4];
                float4 xD = *(const float4*)&xt[(jg + 24) * 68 + h4 * 4];
                #pragma unroll
                for (int kk = 0; kk < 4; kk++) {
                    float qv = qt[ilA * 66 + h4 * 4 + kk];
                    float w  = C4(w4, kk);
                    s0 += w * __builtin_amdgcn_rcpf(1.f + qv * C4(xA, kk));
                    s1 += w * __builtin_amdgcn_rcpf(1.f + qv * C4(xB, kk));
                    s2 += w * __builtin_amdgcn_rcpf(1.f + qv * C4(xC, kk));
                    s3 += w * __builtin_amdgcn_rcpf(1.f + qv * C4(xD, kk));
                }
            }
            {
                int gi = i0 + ilA, gj = j0 + jg;
                St2[(jg     ) * 36 + ilA] = (gj      <= gi && gi < TT) ? s0 : 0.f;
                St2[(jg +  8) * 36 + ilA] = (gj +  8 <= gi && gi < TT) ? s1 : 0.f;
                St2[(jg + 16) * 36 + ilA] = (gj + 16 <= gi && gi < TT) ? s2 : 0.f;
                St2[(jg + 24) * 36 + ilA] = (gj + 24 <= gi && gi < TT) ? s3 : 0.f;
            }
            __syncthreads();
            // stage 2: wave wv owns i-rows il0..il0+7, lane owns e
            #pragma unroll 4
            for (int jl = 0; jl < 32; jl++) {
                float v = pt[jl * 68 + e];
                float4 sA = *(const float4*)&St2[jl * 36 + il0];
                float4 sB = *(const float4*)&St2[jl * 36 + il0 + 4];
                acc[0] += C4(sA,0) * v; acc[1] += C4(sA,1) * v;
                acc[2] += C4(sA,2) * v; acc[3] += C4(sA,3) * v;
                acc[4] += C4(sB,0) * v; acc[5] += C4(sB,1) * v;
                acc[6] += C4(sB,2) * v; acc[7] += C4(sB,3) * v;
            }
        }
    }
    #pragma unroll
    for (int k2 = 0; k2 < 8; k2++) {
        int gi = i0 + il0 + k2;
        if (gi < TT) maP[gi * 4096 + b * 64 + e] = acc[k2];
    }
}

// ---- K4: fused pc+pv heads. 400 blocks x 32 rows, 8 rows/wave, two weight phases ----
// LDS = 32 KB weights + 16 KB acts (layer-0 overwrites in place; pv re-stages).
// tower-a input = sum of S m_a parity slices.
__global__ __launch_bounds__(256) void mlp2_kernel(
    const float* __restrict__ ma, const float* __restrict__ inputs,
    const float* __restrict__ pc_a0k, const float* __restrict__ pc_a0b,
    const float* __restrict__ pc_b0k, const float* __restrict__ pc_b0b,
    const float* __restrict__ pc_a1k, const float* __restrict__ pc_a1b,
    const float* __restrict__ pc_b1k, const float* __restrict__ pc_b1b,
    const float* __restrict__ pv_a0k, const float* __restrict__ pv_a0b,
    const float* __restrict__ pv_b0k, const float* __restrict__ pv_b0b,
    const float* __restrict__ pv_a1k, const float* __restrict__ pv_a1b,
    const float* __restrict__ pv_b1k, const float* __restrict__ pv_b1b,
    float* __restrict__ outp, int S)
{
    __shared__ __align__(16) float wA0[4096], wB0[4096];   // 32 KB
    __shared__ __align__(16) float acts[4][8][2][64];      // 16 KB: raw, then l0 in place
    int t = threadIdx.x, wv = t >> 6, lane = t & 63;
    int tw = lane >> 5, h2 = lane & 31;

    // stage raw activations (wave-private: acts[wv] only touched by wave wv)
    auto stage_acts = [&]() {
        float4* a4 = (float4*)&acts[wv][0][0][0];
        #pragma unroll
        for (int p4 = 0; p4 < 4; p4++) {
            int fw = p4 * 64 + lane;           // 0..255 across the wave
            int r = fw >> 5, src = (fw >> 4) & 1, k4 = fw & 15;
            int row = blockIdx.x * 32 + wv * 8 + r;
            float4 v;
            if (src) {
                v = *(const float4*)&inputs[row * 64 + k4 * 4];
            } else {
                v = *(const float4*)&ma[row * 64 + k4 * 4];
                for (int sl = 1; sl < S; sl++) {
                    float4 u = *(const float4*)&ma[(size_t)sl * SLICE + row * 64 + k4 * 4];
                    v.x += u.x; v.y += u.y; v.z += u.z; v.w += u.w;
                }
            }
            a4[fw] = v;
        }
    };

    stage_acts();
    for (int i = t; i < 4096; i += 256) { wA0[i] = pc_a0k[i]; wB0[i] = pc_b0k[i]; }
    __syncthreads();

    float pcr[8];
    // ---------- phase pc ----------
    {
        float bA = pc_a0b[lane], bB = pc_b0b[lane];
        float accA[8], accB[8];
        #pragma unroll
        for (int r = 0; r < 8; r++) { accA[r] = bA; accB[r] = bB; }
        #pragma unroll 4
        for (int k4 = 0; k4 < 16; k4++) {
            float4 aA[8], aB[8];
            #pragma unroll
            for (int r = 0; r < 8; r++) {
                aA[r] = *(const float4*)&acts[wv][r][0][k4 * 4];
                aB[r] = *(const float4*)&acts[wv][r][1][k4 * 4];
            }
            #pragma unroll
            for (int kk = 0; kk < 4; kk++) {
                float wAv = wA0[(k4 * 4 + kk) * 64 + lane];
                float wBv = wB0[(k4 * 4 + kk) * 64 + lane];
                #pragma unroll
                for (int r = 0; r < 8; r++) {
                    accA[r] += C4(aA[r], kk) * wAv;
                    accB[r] += C4(aB[r], kk) * wBv;
                }
            }
        }
        #pragma unroll
        for (int r = 0; r < 8; r++) {
            acts[wv][r][0][lane] = leaky(accA[r]);
            acts[wv][r][1][lane] = leaky(accB[r]);
        }
        const float* w1p = tw ? pc_b1k : pc_a1k;
        float b1 = (tw ? pc_b1b : pc_a1b)[h2];
        float o[8];
        #pragma unroll
        for (int r = 0; r < 8; r++) o[r] = b1;
        for (int k = 0; k < 64; k++) {
            float w1 = w1p[k * 32 + h2];
            #pragma unroll
            for (int r = 0; r < 8; r++) o[r] += acts[wv][r][tw][k] * w1;
        }
        #pragma unroll
        for (int r = 0; r < 8; r++) {
            float po = leaky(o[r]);
            float pr = po * __shfl_xor(po, 32);
            #pragma unroll
            for (int m = 1; m <= 16; m <<= 1) pr += __shfl_xor(pr, m);
            pcr[r] = pr;    // valid at lane 0
        }
    }
    __syncthreads();   // all waves done with pc weights
    for (int i = t; i < 4096; i += 256) { wA0[i] = pv_a0k[i]; wB0[i] = pv_b0k[i]; }
    stage_acts();      // restore raw acts over l0 (wave-private, no barrier needed)
    __syncthreads();
    // ---------- phase pv ----------
    {
        float bA = pv_a0b[lane], bB = pv_b0b[lane];
        float accA[8], accB[8];
        #pragma unroll
        for (int r = 0; r < 8; r++) { accA[r] = bA; accB[r] = bB; }
        #pragma unroll 4
        for (int k4 = 0; k4 < 16; k4++) {
            float4 aA[8], aB[8];
            #pragma unroll
            for (int r = 0; r < 8; r++) {
                aA[r] = *(const float4*)&acts[wv][r][0][k4 * 4];
                aB[r] = *(const float4*)&acts[wv][r][1][k4 * 4];
            }
            #pragma unroll
            for (int kk = 0; kk < 4; kk++) {
                float wAv = wA0[(k4 * 4 + kk) * 64 + lane];
                float wBv = wB0[(k4 * 4 + kk) * 64 + lane];
                #pragma unroll
                for (int r = 0; r < 8; r++) {
                    accA[r] += C4(aA[r], kk) * wAv;
                    accB[r] += C4(aB[r], kk) * wBv;
                }
            }
        }
        #pragma unroll
        for (int r = 0; r < 8; r++) {
            acts[wv][r][0][lane] = leaky(accA[r]);
            acts[wv][r][1][lane] = leaky(accB[r]);
        }
        const float* w1p = tw ? pv_b1k : pv_a1k;
        float b1 = (tw ? pv_b1b : pv_a1b)[h2];
        float o[8];
        #pragma unroll
        for (int r = 0; r < 8; r++) o[r] = b1;
        for (int k = 0; k < 64; k++) {
            float w1 = w1p[k * 32 + h2];
            #pragma unroll
            for (int r = 0; r < 8; r++) o[r] += acts[wv][r][tw][k] * w1;
        }
        #pragma unroll
        for (int r = 0; r < 8; r++) {
            float po = leaky(o[r]);
            float pr = po * __shfl_xor(po, 32);
            #pragma unroll
            for (int m = 1; m <= 16; m <<= 1) pr += __shfl_xor(pr, m);
            if (lane == 0) {
                int row = blockIdx.x * 32 + wv * 8 + r;
                float spc = sigm_fast(pcr[r]);
                outp[row] = spc;
                outp[TB + row] = sigm_fast(pr) * spc;
            }
        }
    }
}

extern "C" void kernel_launch(void* const* d_in, const int* in_sizes, int n_in,
                              void* d_out, int out_size, void* d_ws, size_t ws_size,
                              hipStream_t stream) {
    const float* inputs = (const float*)d_in[0];
    const float* w1k = (const float*)d_in[1];
    const float* w1b = (const float*)d_in[2];
    const float* w2k = (const float*)d_in[3];
    const float* w3k = (const float*)d_in[4];
    const float* w0k = (const float*)d_in[5];
    float* out = (float*)d_out;
    float* ws  = (float*)d_ws;

    // parity-slice count chosen from ws capacity (constant across calls -> graph-safe)
    size_t avail_f = ws_size / 4;
    int S = 1;
    if      (avail_f >= (size_t)(2 + 4) * SLICE) S = 4;
    else if (avail_f >= (size_t)(2 + 2) * SLICE) S = 2;

    float* x1e  = ws;                  // exp2(-log2e * x1)
    float* qbuf = ws + SLICE;          // x2, then exp2(-log2e * q) in place
    float* y3   = ws + 2 * SLICE;      // y3 until K2; slice 0 of ma after (stream-ordered)
    float* ma   = y3;                  // ma slices p = 0..S-1 at ma + p*SLICE

    gemm3_kernel<<<dim3(800), 256, 0, stream>>>(inputs, w1k, w1b, w2k, w3k, x1e, qbuf, y3);
    cumsum_kernel<<<dim3(128), 256, 0, stream>>>(y3, qbuf);
    scores_kernel<<<dim3(64, 7 * S), 256, 0, stream>>>(x1e, qbuf, inputs, w0k, ma, S);
    mlp2_kernel<<<dim3(400), 256, 0, stream>>>(ma, inputs,
        (const float*)d_in[6],  (const float*)d_in[7],  (const float*)d_in[8],  (const float*)d_in[9],
        (const float*)d_in[10], (const float*)d_in[11], (const float*)d_in[12], (const float*)d_in[13],
        (const float*)d_in[14], (const float*)d_in[15], (const float*)d_in[16], (const float*)d_in[17],
        (const float*)d_in[18], (const float*)d_in[19], (const float*)d_in[20], (const float*)d_in[21],
        out, S);
}